// Round 11
// baseline (157.496 us; speedup 1.0000x reference)
//
#include <hip/hip_runtime.h>

#define N_NODES 100000
#define N_EDGES 600000
#define H 128
#define CAPW 32                                          // words per node line: [0]=count, [1..31]=senders (CAP=31, P(deg>31)~1e-16*N)

// two-level build geometry (R10 counter-proven)
#define NBKT 391                                         // coarse bins of 256 receivers (r>>8)
#define CAP_BIN 2048                                     // records per bin (mean 1536, +13 sigma)
#define TAILPAD 32                                       // bin_tails padded to 1 line/bin
#define NQ (N_EDGES / 4)                                 // 150000 edge quads (exact)

// prep grid (1024-thr blocks)
#define NB_FILL1 147                                     // 4096 edges/block
#define NB_BPERM 4
#define NB_CONV 782                                      // 4096 float4 each (last partial)
#define NB_TOTAL (NB_FILL1 + NB_BPERM + NB_CONV)         // 933

#define BLK_NODES 32
#define N_BLKS (N_NODES / BLK_NODES)                     // 3125 EXACT -> no bounds checks in gather

typedef short v8s __attribute__((ext_vector_type(8)));   // 8 bf16 (4 VGPRs)
typedef float v4f __attribute__((ext_vector_type(4)));   // 4 fp32 (native vector: OK for NT builtins)

__device__ __forceinline__ unsigned short f2bf(float f) {
    unsigned int u = __float_as_uint(f);
    u = (u + 0x7fffu + ((u >> 16) & 1u)) >> 16;   // round-nearest-even
    return (unsigned short)u;
}
__device__ __forceinline__ unsigned int pack2bf(float a, float b) {
    return (unsigned int)f2bf(a) | ((unsigned int)f2bf(b) << 16);
}
__device__ __forceinline__ void accum8(float* a, uint4 u) {
    a[0] += __uint_as_float(u.x << 16);
    a[1] += __uint_as_float(u.x & 0xffff0000u);
    a[2] += __uint_as_float(u.y << 16);
    a[3] += __uint_as_float(u.y & 0xffff0000u);
    a[4] += __uint_as_float(u.z << 16);
    a[5] += __uint_as_float(u.z & 0xffff0000u);
    a[6] += __uint_as_float(u.w << 16);
    a[7] += __uint_as_float(u.w & 0xffff0000u);
}

__device__ __forceinline__ void bperm_fill(int tt, const float* Ws, const float* Wm,
                                           unsigned short* Bperm) {
    // B-fragment permute: frag f=(kstep*8+ntile)*64+lane holds
    // B[k=kstep*32+q*8+j][n=ntile*16+(lane&15)], B=[Ws;Wm] (K=256,N=128)
    int kstep = tt >> 9;
    int ntile = (tt >> 6) & 7;
    int lane  = tt & 63;
    int q = lane >> 4;
    int n = ntile * 16 + (lane & 15);
#pragma unroll
    for (int j = 0; j < 8; ++j) {
        int k = kstep * 32 + q * 8 + j;
        float v = (k < H) ? Ws[k * H + n] : Wm[(k - H) * H + n];
        Bperm[(size_t)tt * 8 + j] = f2bf(v);
    }
}

// ---------------------------------------------------------------------------
// Prep — R10 verbatim (counter-proven: LDS-histogram level-1 build cut global
// atomics 600k -> 57k and took prep out of the top-5; the R2/R4/R5 bracket
// proved per-op RMW throughput is the wall, so only fewer ops win).
// ---------------------------------------------------------------------------
__global__ __launch_bounds__(1024) void prep_fused_kernel(
    const float* __restrict__ x, unsigned int* __restrict__ xb4,
    const float* __restrict__ Ws, const float* __restrict__ Wm,
    unsigned short* __restrict__ Bperm,
    const int* __restrict__ senders, const int* __restrict__ receivers,
    int* __restrict__ bin_tails, unsigned int* __restrict__ lists)
{
    const int b = blockIdx.x;
    const int tid = threadIdx.x;

    if (b < NB_FILL1) {
        __shared__ int hist[NBKT];
        __shared__ int base[NBKT];
        for (int i = tid; i < NBKT; i += 1024) hist[i] = 0;
        __syncthreads();

        const int qi = b * 1024 + tid;             // edge quad index
        int4 r4, s4;
        const bool act = (qi < NQ);
        if (act) {
            r4 = ((const int4*)receivers)[qi];
            s4 = ((const int4*)senders)[qi];
            atomicAdd(&hist[r4.x >> 8], 1);
            atomicAdd(&hist[r4.y >> 8], 1);
            atomicAdd(&hist[r4.z >> 8], 1);
            atomicAdd(&hist[r4.w >> 8], 1);
        }
        __syncthreads();
        for (int i = tid; i < NBKT; i += 1024) {
            int h = hist[i];
            base[i] = (h > 0) ? atomicAdd(&bin_tails[i * TAILPAD], h) : 0;
            hist[i] = 0;                           // reuse as pass-2 rank counter
        }
        __syncthreads();
        if (act) {
            int r[4] = {r4.x, r4.y, r4.z, r4.w};
            int s[4] = {s4.x, s4.y, s4.z, s4.w};
#pragma unroll
            for (int k = 0; k < 4; ++k) {
                int bin = r[k] >> 8;
                int rank = atomicAdd(&hist[bin], 1);
                int idx = base[bin] + rank;
                if (idx < CAP_BIN)
                    lists[(size_t)bin * CAP_BIN + idx] =
                        ((unsigned int)s[k] << 8) | (unsigned int)(r[k] & 255);
            }
        }
    } else if (b < NB_FILL1 + NB_BPERM) {
        int tt = (b - NB_FILL1) * 1024 + tid;      // 0..4095
        bperm_fill(tt, Ws, Wm, Bperm);
    } else {
        int base4 = (b - NB_FILL1 - NB_BPERM) * 4096 + tid;
#pragma unroll
        for (int k = 0; k < 4; ++k) {
            int i = base4 + k * 1024;              // float4 index
            if (i < N_NODES * H / 4) {
                float4 v = ((const float4*)x)[i];
                uint2 ov;
                ov.x = pack2bf(v.x, v.y);
                ov.y = pack2bf(v.z, v.w);
                ((uint2*)xb4)[i] = ov;
            }
        }
    }
}

// ---------------------------------------------------------------------------
// Level-2 placement. R11 change: writes the MERGED line layout
// lines[node*32] = [count, s0..s30] so gather's first int4 load yields
// count + 3 senders (one dependent-load level removed). The separate cnt
// array dies. Region per block is still one contiguous 32KB range.
// ---------------------------------------------------------------------------
__global__ __launch_bounds__(256) void place_kernel(
    const int* __restrict__ bin_tails, const unsigned int* __restrict__ lists,
    int* __restrict__ slots)
{
    __shared__ int fc[256];
    const int bin = blockIdx.x;
    const int tid = threadIdx.x;
    fc[tid] = 0;
    __syncthreads();

    int tl = bin_tails[bin * TAILPAD];
    if (tl > CAP_BIN) tl = CAP_BIN;
    const unsigned int* lp = lists + (size_t)bin * CAP_BIN;
    const int base_rid = bin << 8;
    for (int i = tid; i < tl; i += 256) {
        unsigned int e = lp[i];
        int rl = (int)(e & 255u);
        int s  = (int)(e >> 8);
        int pos = atomicAdd(&fc[rl], 1);
        if (pos < 31) slots[(size_t)(base_rid + rl) * CAPW + 1 + pos] = s;
    }
    __syncthreads();
    int rid = base_rid + tid;
    if (rid < N_NODES) slots[(size_t)rid * CAPW] = fc[tid];
}

// ---------------------------------------------------------------------------
// Fused gather + MFMA GEMM. R11 changes (gather FETCH-floor package):
// 1) 32-node tiles x 512 thr: wave w gathers exactly 4 nodes (no g loop) ->
//    block latency ~halves -> drain tail ~halves. 3125 blocks, exact divide,
//    all bounds checks gone. Still 4 blocks/CU x 8 waves = 32 waves (100%).
// 2) Conflict-free LDS: tile16[buf][node][chunk^(node&15)] (contiguous 256B
//    per node, XOR chunk swizzle). Writes: 16 lanes cover one node row ->
//    2/bank free. Reads: lic^mr spreads -> 2/bank free. No pad: LDS 16,384B
//    (was 33,280 with 2.0M conflict-cycles = 1280/block structural).
// 3) Merged line [count|senders]: first int4 gives count+3 senders; batches
//    of 4 follow 16B-aligned (k=3,7,..). Mean deg 6 -> 2 loads total.
// ---------------------------------------------------------------------------
__global__ __launch_bounds__(512) void gather_gemm_kernel(
    const unsigned short* __restrict__ xb,
    const int* __restrict__ lines,
    const unsigned short* __restrict__ Bperm,
    const float* __restrict__ bias,
    float* __restrict__ out)
{
    __shared__ __align__(16) unsigned char smem[16384];  // tile16 | reuse: orow
    uint4 (*tile16)[BLK_NODES][16] = (uint4(*)[BLK_NODES][16])smem;  // [2][32][16]
    float (*orow)[H] = (float(*)[H])smem;                // 32x128 f32 = 16KB

    const int t = threadIdx.x;
    const int w = t >> 6;              // 0..7
    const int lane = t & 63;
    const int node_base = blockIdx.x * BLK_NODES;
    const int sub = (lane >> 4) & 3;   // node within wave's group of 4
    const int li  = lane & 15;         // column chunk (8 bf16 = 16 B)

    // ---- Phase A: wave w gathers nodes [w*4, w*4+4) ----
    {
        const int nl = w * 4 + sub;                // node_local 0..31
        const int node = node_base + nl;
        const int* ln = lines + (size_t)node * CAPW;
        int4 h = *(const int4*)ln;                 // [count, s0, s1, s2]
        uint4 xcopy = *(const uint4*)(xb + (size_t)node * H + li * 8);
        const int d_true = h.x;
        const int d = d_true < 31 ? d_true : 31;
        float a[8];
#pragma unroll
        for (int i = 0; i < 8; ++i) a[i] = 0.f;
        if (d > 0) accum8(a, *(const uint4*)(xb + (size_t)h.y * H + li * 8));
        if (d > 1) accum8(a, *(const uint4*)(xb + (size_t)h.z * H + li * 8));
        if (d > 2) accum8(a, *(const uint4*)(xb + (size_t)h.w * H + li * 8));
        int k = 3;
        for (; k + 3 < d; k += 4) {                // ln+1+k: k=3,7,.. -> 16B aligned
            int4 i4 = *(const int4*)(ln + 1 + k);
            uint4 u0 = *(const uint4*)(xb + (size_t)i4.x * H + li * 8);
            uint4 u1 = *(const uint4*)(xb + (size_t)i4.y * H + li * 8);
            uint4 u2 = *(const uint4*)(xb + (size_t)i4.z * H + li * 8);
            uint4 u3 = *(const uint4*)(xb + (size_t)i4.w * H + li * 8);
            accum8(a, u0);
            accum8(a, u1);
            accum8(a, u2);
            accum8(a, u3);
        }
        for (; k < d; ++k)
            accum8(a, *(const uint4*)(xb + (size_t)ln[1 + k] * H + li * 8));

        float inv = 1.0f / fmaxf((float)d_true, 1.0f);
        uint4 o;
        o.x = pack2bf(a[0] * inv, a[1] * inv);
        o.y = pack2bf(a[2] * inv, a[3] * inv);
        o.z = pack2bf(a[4] * inv, a[5] * inv);
        o.w = pack2bf(a[6] * inv, a[7] * inv);
        const int cs = li ^ (nl & 15);             // XOR chunk swizzle
        tile16[0][nl][cs] = xcopy;
        tile16[1][nl][cs] = o;
    }
    __syncthreads();

    // ---- Phase B: GEMM, wave w owns n-tile w (32 rows x 16 cols) ----
    const int q  = lane >> 4;
    const int mr = lane & 15;

    v4f acc[2];
    {
        float bv = bias[w * 16 + mr];
        acc[0] = (v4f){bv, bv, bv, bv};
        acc[1] = (v4f){bv, bv, bv, bv};
    }
    const v8s* bp = (const v8s*)Bperm;
#pragma unroll
    for (int ks = 0; ks < 8; ++ks) {
        int buf = ks >> 2;                 // 0: x-part (K 0..127), 1: agg-part
        int lic = (ks & 3) * 4 + q;        // chunk holding cols [ks*32+q*8, +8)
        // node n chunk lic lives at [n][lic ^ (n&15)]; (16+mr)&15 == mr
        v8s a0 = *(const v8s*)&tile16[buf][mr][lic ^ mr];
        v8s a1 = *(const v8s*)&tile16[buf][16 + mr][lic ^ mr];
        v8s bfrag = bp[(ks * 8 + w) * 64 + lane];
        acc[0] = __builtin_amdgcn_mfma_f32_16x16x32_bf16(a0, bfrag, acc[0], 0, 0, 0);
        acc[1] = __builtin_amdgcn_mfma_f32_16x16x32_bf16(a1, bfrag, acc[1], 0, 0, 0);
    }

    // ---- Epilogue: stage ReLU'd tile in LDS, stream out as full lines ----
    __syncthreads();   // tile16 reads done; safe to overwrite as orow
#pragma unroll
    for (int s = 0; s < 2; ++s) {
#pragma unroll
        for (int r = 0; r < 4; ++r) {
            int row = s * 16 + q * 4 + r;
            int colx = (w * 16 + mr) ^ (q << 2);   // (row>>2)&3 == q for r<4
            orow[row][colx] = fmaxf(acc[s][r], 0.f);
        }
    }
    __syncthreads();

    v4f* out4 = (v4f*)(out + (size_t)node_base * H);
#pragma unroll
    for (int k = 0; k < 2; ++k) {
        int j = t + k * 512;               // 0..1023 over 32 rows x 32 float4
        int row = j >> 5;
        int c4  = j & 31;
        int xr = (row >> 2) & 3;
        v4f v = *(const v4f*)&orow[row][(c4 ^ xr) << 2];
        __builtin_nontemporal_store(v, &out4[j]);
    }
}

extern "C" void kernel_launch(void* const* d_in, const int* in_sizes, int n_in,
                              void* d_out, int out_size, void* d_ws, size_t ws_size,
                              hipStream_t stream) {
    const float* x        = (const float*)d_in[0];
    const int*   senders  = (const int*)d_in[1];
    const int*   receivers= (const int*)d_in[2];
    const float* Ws       = (const float*)d_in[3];
    const float* Wm       = (const float*)d_in[4];
    const float* bias     = (const float*)d_in[5];
    float*       out      = (float*)d_out;

    // workspace layout (~41.7 MB)
    char* p = (char*)d_ws;
    unsigned short* xb    = (unsigned short*)p; p += (size_t)N_NODES * H * sizeof(unsigned short); // 25.6 MB
    unsigned short* Bperm = (unsigned short*)p; p += (size_t)256 * H * sizeof(unsigned short);     // 64 KB
    int* slots = (int*)p; p += (size_t)N_NODES * CAPW * sizeof(int);                               // 12.8 MB (count+senders lines)
    int* bin_tails = (int*)p; p += (size_t)NBKT * TAILPAD * sizeof(int);                           // 50 KB
    unsigned int* lists = (unsigned int*)p; p += (size_t)NBKT * CAP_BIN * sizeof(unsigned int);    // 3.2 MB

    (void)hipMemsetAsync(bin_tails, 0, (size_t)NBKT * TAILPAD * sizeof(int), stream);

    prep_fused_kernel<<<NB_TOTAL, 1024, 0, stream>>>(
        x, (unsigned int*)xb, Ws, Wm, Bperm, senders, receivers, bin_tails, lists);
    place_kernel<<<NBKT, 256, 0, stream>>>(bin_tails, lists, slots);
    gather_gemm_kernel<<<N_BLKS, 512, 0, stream>>>(xb, slots, Bperm, bias, out);
}